// Round 16
// baseline (2330.658 us; speedup 1.0000x reference)
//
#include <hip/hip_runtime.h>

using u16 = unsigned short;
using u32 = unsigned int;
using u64 = unsigned long long;
using bf16x8 = __attribute__((ext_vector_type(8))) short;
using f16x8  = __attribute__((ext_vector_type(8))) _Float16;
using f32x4  = __attribute__((ext_vector_type(4))) float;
using u32x4  = __attribute__((ext_vector_type(4))) unsigned int;

// ---------------- workspace layout (bytes) ----------------
static constexpr size_t XU_OFF = 0;
static constexpr size_t XU_BYTES = (size_t)512 * 64 * 4096 * 2;      // 256 MiB
static constexpr size_t XB_OFF = XU_OFF + XU_BYTES;
static constexpr size_t XB_BYTES = (size_t)64 * 512 * 1024 * 2;      // 64 MiB
static constexpr size_t UT_OFF = XB_OFF + XB_BYTES;
static constexpr size_t WT_BYTES = (size_t)4096 * 1024 * 2;          // 8 MiB
static constexpr size_t VT_OFF = UT_OFF + WT_BYTES;
static constexpr size_t BP_OFF = VT_OFF + WT_BYTES;
static constexpr size_t BP_BYTES = 4096 * 4;
// h plane: [2 parity][4 group][16 row][1024 col] u16 (fp16)
static constexpr size_t HT_PLANE = (size_t)2 * 4 * 16 * 1024 * 2;    // 256 KiB
static constexpr size_t HHI_OFF = BP_OFF + BP_BYTES;
static constexpr size_t FLAG_OFF = HHI_OFF + HT_PLANE;
static constexpr size_t FLAG_BYTES = 4096;   // flags[g*64+cb] (1KB) + chunk cnt[4] @ +2048

__device__ __forceinline__ float bf2f(u32 u) {
    return __uint_as_float(u << 16);
}
__device__ __forceinline__ u16 f2bf(float f) {
    u32 u = __float_as_uint(f);
    u32 r = (u + 0x7FFFu + ((u >> 16) & 1u)) >> 16;
    return (u16)r;
}
__device__ __forceinline__ u16 f2h(float f) {
    _Float16 x = (_Float16)f;                     // RTN
    union { _Float16 h; u16 u; } cv;
    cv.h = x;
    return cv.u;
}

// fast gates: v_exp + v_rcp (err ~1e-7, far below bf16 pipeline noise)
__device__ __forceinline__ float fast_sigmoid(float x) {
    return __builtin_amdgcn_rcpf(1.f + __expf(-x));
}
__device__ __forceinline__ float fast_tanh(float x) {
    return 1.f - 2.f * __builtin_amdgcn_rcpf(1.f + __expf(2.f * x));
}

// 16B cache-bypassing load (full-64B-line MALL requests)
__device__ __forceinline__ u32x4 load16_uc(const u16* p) {
    u32x4 v;
    asm volatile("global_load_dwordx4 %0, %1, off sc0 sc1"
                 : "=v"(v)
                 : "v"(p));
    return v;
}

// 16B write-through store, MALL-ALLOCATING (sc0 sc1, no nt). Required for
// cross-XCD produce/consume of xu inside ONE kernel. Ledger: nt bypasses MALL
// allocation (consumer reads become HBM misses, +450us, R7); plain cached
// stores thrash MALL with dirty writebacks (FETCH 1.38GB, R8).
__device__ __forceinline__ void store16_wt(u16* p, u32x4 v) {
    asm volatile("global_store_dwordx4 %0, %1, off sc0 sc1"
                 :: "v"(p), "v"(v) : "memory");
}

// counted wait for h load j (4 loads issued; xu prefetch may be outstanding
// and is OLDER, so vmcnt(3-j) drains it first -- oldest-first is safe).
__device__ __forceinline__ void wait_vm4(int j, u32x4& a) {
    switch (j) {
    case 0:  asm volatile("s_waitcnt vmcnt(3)" : "+v"(a)); break;
    case 1:  asm volatile("s_waitcnt vmcnt(2)" : "+v"(a)); break;
    case 2:  asm volatile("s_waitcnt vmcnt(1)" : "+v"(a)); break;
    default: asm volatile("s_waitcnt vmcnt(0)" : "+v"(a)); break;
    }
}

// async global->LDS, 16B per lane (wave-uniform LDS base + lane*16)
__device__ __forceinline__ void gld16(const u16* g, u16* l) {
    __builtin_amdgcn_global_load_lds((const __attribute__((address_space(1))) void*)g,
                                     (__attribute__((address_space(3))) void*)l,
                                     16, 0, 0);
}

// xu t-chunk readiness gate (2048 tiles per chunk)
__device__ __forceinline__ void wait_chunk(const u32* cnt, int c) {
    for (;;) {
        u32 v = __hip_atomic_load(cnt + c, __ATOMIC_RELAXED, __HIP_MEMORY_SCOPE_AGENT);
        if (v >= 2048u) break;
        __builtin_amdgcn_s_sleep(8);
    }
    asm volatile("" ::: "memory");   // keep xu loads below the gate
}

// ------------- merged prep: cvt_x + U/V repack + bias pack + flag zero -------------
__global__ void __launch_bounds__(256) prep_kernel(
        const float* __restrict__ x,
        const float* U0, const float* U1, const float* U2, const float* U3,
        const float* V0, const float* V1, const float* V2, const float* V3,
        const float* b0, const float* b1, const float* b2, const float* b3,
        u16* __restrict__ xb, u16* __restrict__ UT, u16* __restrict__ VT,
        float* __restrict__ bp, u32* __restrict__ flags) {
    __shared__ u16 tile[64][65];
    int bx = blockIdx.x;
    int tid = threadIdx.x;

    if (bx < 4096) {            // ---- x fp32 -> bf16 ----
        const float4* x4 = (const float4*)x;
        uint2* xb4 = (uint2*)xb;
        int i = bx * 256 + tid;
#pragma unroll
        for (int k = 0; k < 8; ++k) {
            int idx = i + k * 1048576;
            float4 v = x4[idx];
            uint2 o;
            o.x = (u32)f2bf(v.x) | ((u32)f2bf(v.y) << 16);
            o.y = (u32)f2bf(v.z) | ((u32)f2bf(v.w) << 16);
            xb4[idx] = o;
        }
    } else if (bx < 6144) {     // ---- U/V repack (U->bf16, V->fp16) ----
        int rbx = bx - 4096;
        int mat = rbx >> 8;
        int rem = rbx & 255;
        int tf = rem >> 4, th = rem & 15;
        int f0 = tf * 64, h0 = th * 64;
        const float* srcs[8] = {U0, U1, U2, U3, V0, V1, V2, V3};
        const float* s = srcs[mat];
        u16* d = (mat < 4) ? UT : VT;
        bool isU = (mat < 4);
        int g = mat & 3;
        int c = tid & 63;
        int r = tid >> 6;
#pragma unroll
        for (int i = 0; i < 16; ++i) {
            int fr = r + i * 4;
            float v = s[(size_t)(f0 + fr) * 1024 + h0 + c];
            tile[fr][c] = isU ? f2bf(v) : f2h(v);
        }
        __syncthreads();
#pragma unroll
        for (int i = 0; i < 16; ++i) {
            int hcl = r + i * 4;
            d[(size_t)((h0 + hcl) * 4 + g) * 1024 + f0 + c] = tile[c][hcl];
        }
    } else if (bx < 6160) {     // ---- bias pack ----
        int n = (bx - 6144) * 256 + tid;
        int g = n & 3, hc = n >> 2;
        const float* bs[4] = {b0, b1, b2, b3};
        bp[n] = bs[g][hc];
    } else {                    // ---- zero flags + chunk counters ----
#pragma unroll
        for (int k = 0; k < 4; ++k)
            __hip_atomic_store(flags + tid * 4 + k, 0u, __ATOMIC_RELAXED,
                               __HIP_MEMORY_SCOPE_AGENT);
    }
}

// ------------- one 128x128 xU GEMM tile, 8 waves, double-buffered staging -------------
// R13 version (linear LDS, no swizzle -- R15 proved the 8-way conflicts are
// hidden by the lockstep structure; swizzle's addr-VALU cost ~50us). Chunk-
// ordered tile index tau: tc=tau>>11, b=(tau&2047)>>5, nt=tau&31, mt=b*4+tc.
__device__ __forceinline__ void gemm_tile(int tau,
        const u16* __restrict__ xb, const u16* __restrict__ UT,
        const float* __restrict__ bp, u16* __restrict__ xu,
        u16* As, u16* Bs, u16* Cs, u32* cnt) {
    int tc = tau >> 11, rem = tau & 2047;
    int b = rem >> 5, nt = rem & 31, mt = b * 4 + tc;
    int tid = threadIdx.x;
    int lane = tid & 63, wv = tid >> 6;
    int wm = wv >> 2, wn = wv & 3;                // 2 x 4 wave grid
    int l15 = lane & 15, quad = lane >> 4;

    int idr = tid >> 2, idk = (tid & 3) * 8;
    const u16* aS = xb + (size_t)(mt * 128 + idr) * 1024 + idk;
    const u16* bS = UT + (size_t)(nt * 128 + idr) * 1024 + idk;

    f32x4 acc[4][2];
#pragma unroll
    for (int i = 0; i < 4; ++i)
#pragma unroll
        for (int j = 0; j < 2; ++j) acc[i][j] = f32x4{0.f, 0.f, 0.f, 0.f};

    float biasv[2];
#pragma unroll
    for (int j = 0; j < 2; ++j) biasv[j] = bp[nt * 128 + wn * 32 + j * 16 + l15];

    // prologue: stage K-step 0 into buffer 0
    gld16(aS, As + (size_t)tid * 8);
    gld16(bS, Bs + (size_t)tid * 8);

    for (int s = 0; s < 32; ++s) {
        int cur = s & 1;
        const u16* Ab = As + cur * 4096;
        const u16* Bb = Bs + cur * 4096;
        __syncthreads();                          // drains buf[cur] loads
        if (s + 1 < 32) {                         // issue next K-step into buf[cur^1]
            int k0 = (s + 1) * 32;
            gld16(aS + k0, As + (cur ^ 1) * 4096 + (size_t)tid * 8);
            gld16(bS + k0, Bs + (cur ^ 1) * 4096 + (size_t)tid * 8);
        }
        bf16x8 af[4], bfv[2];
#pragma unroll
        for (int i = 0; i < 4; ++i)
            af[i] = *(const bf16x8*)(Ab + (size_t)(wm * 64 + i * 16 + l15) * 32 + quad * 8);
#pragma unroll
        for (int j = 0; j < 2; ++j)
            bfv[j] = *(const bf16x8*)(Bb + (size_t)(wn * 32 + j * 16 + l15) * 32 + quad * 8);
#pragma unroll
        for (int i = 0; i < 4; ++i)
#pragma unroll
            for (int j = 0; j < 2; ++j)
                acc[i][j] = __builtin_amdgcn_mfma_f32_16x16x32_bf16(af[i], bfv[j], acc[i][j], 0, 0, 0);
    }
    __syncthreads();                              // all waves done with As/Bs reads

    // acc -> LDS C-tile (row-pad 136 u16 kills the 64-aligned bank repeat)
#pragma unroll
    for (int i = 0; i < 4; ++i)
#pragma unroll
        for (int j = 0; j < 2; ++j)
#pragma unroll
            for (int rg = 0; rg < 4; ++rg)
                Cs[(size_t)(wm * 64 + i * 16 + quad * 4 + rg) * 136 + wn * 32 + j * 16 + l15] =
                    f2bf(acc[i][j][rg] + biasv[j]);
    __syncthreads();

    // coalesced write-through: 16 lanes cover one 256B row-segment
#pragma unroll
    for (int p = 0; p < 4; ++p) {
        int id = p * 512 + tid;
        int row = id >> 4, q = id & 15;
        u32x4 v = *(const u32x4*)(Cs + (size_t)row * 136 + q * 8);
        int gr = mt * 128 + row;
        int t_i = gr & 511, b_i = gr >> 9;
        store16_wt(xu + (((size_t)(t_i * 64 + b_i)) << 12) + nt * 128 + q * 8, v);
    }
    asm volatile("s_waitcnt vmcnt(0)" ::: "memory");
    __syncthreads();                              // all waves' stores MALL-acked
    if (tid == 0)
        __hip_atomic_fetch_add(cnt + tc, 1u, __ATOMIC_RELAXED, __HIP_MEMORY_SCOPE_AGENT);
}

// ------------- fused kernel: xU GEMM overlapped with the recurrent scan -------------
// 256 blocks x 512 threads, 1/CU (132KB LDS). PHASE A now builds chunks 0 AND
// 1 serially on the full GPU (~140us, zero interference): R11 showed scan
// interference ~ linear in overlap traffic volume, and R6 measured ~290us
// inflation for a 48-tile phase B -- halving phase B to chunks 2..3 (32
// tiles/block) should halve interference (~145us) for +70us serial cost.
// Deadlines: scan needs chunk 2 at ~960us; phase B finishes it ~270us.
__global__ void __launch_bounds__(512, 2) lstm_fused_kernel(
        const u16* __restrict__ xb, const u16* __restrict__ UT,
        const float* __restrict__ bp, u16* __restrict__ xu,
        const u16* __restrict__ VT, u16* hhi, u32* flags, u32* cnt,
        float* __restrict__ out) {
    __shared__ u16 As[2 * 128 * 32];              // 16 KB (double-buffered)
    __shared__ u16 Bs[2 * 128 * 32];              // 16 KB
    __shared__ u16 Cs[128 * 136];                 // 34 KB
    __shared__ float zs[8][16][132];              // 67.6 KB

    int bx = blockIdx.x;

    // ---- PHASE A: chunks 0 AND 1 on the full GPU (serial) ----
    for (int p = 0; p < 8; ++p)
        gemm_tile(bx * 8 + p, xb, UT, bp, xu, As, Bs, Cs, cnt);
    for (int p = 0; p < 8; ++p)
        gemm_tile(2048 + bx * 8 + p, xb, UT, bp, xu, As, Bs, Cs, cnt);

    if (bx >= 128) {
        // ---- PHASE B: chunks 2..3 on blocks 128..255 ----
        int gid = bx - 128;
        for (int p = 0; p < 32; ++p)
            gemm_tile(4096 + p * 128 + gid, xb, UT, bp, xu, As, Bs, Cs, cnt);
        return;
    }

    // ---- recurrent scan (round-5 proven structure) ----
    int g  = bx & 3;
    int cb = bx >> 2;                             // 0..31
    int tid = threadIdx.x;
    int lane = tid & 63, wv = tid >> 6;           // wv 0..7
    int l15 = lane & 15, quad = lane >> 4;
    int r  = tid >> 5;                            // batch row within group, 0..15
    int hc = tid & 31;                            // h-col within block, 0..31

    // V fragments in registers (fp16, 128 VGPRs/lane, fixed across steps)
    f16x8 vfrag[8][4];
    {
        const u16* vb = VT + ((size_t)(cb * 128 + l15) * 1024) + wv * 128 + quad * 8;
#pragma unroll
        for (int nt = 0; nt < 8; ++nt)
#pragma unroll
            for (int j = 0; j < 4; ++j)
                vfrag[nt][j] = *(const f16x8*)(vb + (size_t)nt * 16 * 1024 + j * 32);
    }

    u32* gflags = flags + g * 64;
    int myp = 4 * wv + (lane & 3);                // producer polled by this lane

    float c = 0.f;
    float h = 0.f;

    wait_chunk(cnt, 0);
    uint2 xraw = *(const uint2*)(xu + ((size_t)(g * 16 + r) << 12) + cb * 128 + hc * 4);

    for (int t = 0; t < 512; ++t) {
        f32x4 acc[8];
#pragma unroll
        for (int nt = 0; nt < 8; ++nt) acc[nt] = f32x4{0.f, 0.f, 0.f, 0.f};

        if (t) {
            // 1) poll this wave's 4 producers (lanes replicate x16; ballot all-set)
            for (;;) {
                u32 f = __hip_atomic_load(gflags + myp, __ATOMIC_RELAXED,
                                          __HIP_MEMORY_SCOPE_AGENT);
                if (__ballot(f >= (u32)t) == ~0ull) break;
                __builtin_amdgcn_s_sleep(1);
            }
            asm volatile("" ::: "memory");        // keep h loads below the poll

            // 2) stream h fragments: 4x16B uncached loads, full-line MALL reads
            const u16* hB = hhi + (((size_t)(t & 1) * 4 + g) * 16 + l15) * 1024
                          + wv * 128 + quad * 8;
            u32x4 hv[4];
#pragma unroll
            for (int j = 0; j < 4; ++j)
                hv[j] = load16_uc(hB + j * 32);
#pragma unroll
            for (int j = 0; j < 4; ++j) {
                wait_vm4(j, hv[j]);               // counted wait, ties block MFMA hoist
                union { u32x4 q; f16x8 v; } ah;
                ah.q = hv[j];
#pragma unroll
                for (int nt = 0; nt < 8; ++nt)
                    acc[nt] = __builtin_amdgcn_mfma_f32_16x16x32_f16(ah.v, vfrag[nt][j], acc[nt], 0, 0, 0);
            }
        }

        // 3) split-K partial handoff: C layout col=l15, row=quad*4+rg
#pragma unroll
        for (int nt = 0; nt < 8; ++nt)
#pragma unroll
            for (int rg = 0; rg < 4; ++rg)
                zs[wv][quad * 4 + rg][nt * 16 + l15] = acc[nt][rg];
        __syncthreads();

        float4 s = {0.f, 0.f, 0.f, 0.f};
#pragma unroll
        for (int w = 0; w < 8; ++w) {
            float4 v = *(const float4*)&zs[w][r][hc * 4];
            s.x += v.x; s.y += v.y; s.z += v.z; s.w += v.w;
        }
        float z0 = s.x + bf2f(xraw.x & 0xFFFFu);
        float z1 = s.y + bf2f(xraw.x >> 16);
        float z2 = s.z + bf2f(xraw.y & 0xFFFFu);
        float z3 = s.w + bf2f(xraw.y >> 16);

        float it_ = fast_sigmoid(z0);
        float ft_ = fast_sigmoid(z1);
        float gt_ = fast_tanh(z2);
        float ot_ = fast_tanh(z3);   // reference uses tanh for output gate
        c = ft_ * c + it_ * gt_;
        h = ot_ * fast_tanh(c);

        if (t == 511) break;     // final h never read back

        // 4) publish h (single fp16 write-through) + drain (stores only) + flag
        size_t sidx = (((size_t)((t + 1) & 1) * 4 + g) * 16 + r) * 1024 + cb * 32 + hc;
        __hip_atomic_store(hhi + sidx, f2h(h), __ATOMIC_RELAXED,
                           __HIP_MEMORY_SCOPE_AGENT);
        asm volatile("s_waitcnt vmcnt(0)" ::: "memory");
        __syncthreads();          // also protects zs reuse next iteration
        if (tid == 0)
            __hip_atomic_store(gflags + cb, (u32)(t + 1), __ATOMIC_RELAXED,
                               __HIP_MEMORY_SCOPE_AGENT);

        // 5) prefetch next xu AFTER the flag (chunk-gated every 128 steps;
        //    gate is after the flag store so it never extends the publish path)
        if (((t + 1) & 127) == 0) wait_chunk(cnt, (t + 1) >> 7);
        xraw = *(const uint2*)(xu + ((size_t)((t + 1) * 64 + g * 16 + r) << 12) + cb * 128 + hc * 4);
    }

    out[(size_t)(g * 16 + r) * 1024 + cb * 32 + hc] = h;
}

extern "C" void kernel_launch(void* const* d_in, const int* in_sizes, int n_in,
                              void* d_out, int out_size, void* d_ws, size_t ws_size,
                              hipStream_t stream) {
    char* ws = (char*)d_ws;
    const float* x = (const float*)d_in[0];
    const float *U[4], *V[4], *b[4];
    for (int g = 0; g < 4; ++g) {
        U[g] = (const float*)d_in[1 + 3 * g];
        V[g] = (const float*)d_in[2 + 3 * g];
        b[g] = (const float*)d_in[3 + 3 * g];
    }
    u16*   xu = (u16*)(ws + XU_OFF);
    u16*   xb = (u16*)(ws + XB_OFF);
    u16*   UT = (u16*)(ws + UT_OFF);
    u16*   VT = (u16*)(ws + VT_OFF);
    float* bp = (float*)(ws + BP_OFF);
    u16*   hhi = (u16*)(ws + HHI_OFF);
    u32*   flags = (u32*)(ws + FLAG_OFF);
    u32*   cnt = (u32*)(ws + FLAG_OFF + 2048);
    float* out = (float*)d_out;

    // ONE prep launch: cvt + repack + bias + flag/cnt zero
    prep_kernel<<<6161, 256, 0, stream>>>(x,
                                          U[0], U[1], U[2], U[3],
                                          V[0], V[1], V[2], V[3],
                                          b[0], b[1], b[2], b[3],
                                          xb, UT, VT, bp, flags);

    void* args[] = {(void*)&xb, (void*)&UT, (void*)&bp, (void*)&xu,
                    (void*)&VT, (void*)&hhi, (void*)&flags, (void*)&cnt,
                    (void*)&out};
    hipLaunchCooperativeKernel((const void*)lstm_fused_kernel, dim3(256), dim3(512),
                               args, 0, stream);
}

// Round 17
// 2144.533 us; speedup vs baseline: 1.0868x; 1.0868x over previous
//
#include <hip/hip_runtime.h>

using u16 = unsigned short;
using u32 = unsigned int;
using u64 = unsigned long long;
using bf16x8 = __attribute__((ext_vector_type(8))) short;
using f16x8  = __attribute__((ext_vector_type(8))) _Float16;
using f32x4  = __attribute__((ext_vector_type(4))) float;
using u32x4  = __attribute__((ext_vector_type(4))) unsigned int;

// ---------------- workspace layout (bytes) ----------------
static constexpr size_t XU_OFF = 0;
static constexpr size_t XU_BYTES = (size_t)512 * 64 * 4096 * 2;      // 256 MiB
static constexpr size_t XB_OFF = XU_OFF + XU_BYTES;
static constexpr size_t XB_BYTES = (size_t)64 * 512 * 1024 * 2;      // 64 MiB
static constexpr size_t UT_OFF = XB_OFF + XB_BYTES;
static constexpr size_t WT_BYTES = (size_t)4096 * 1024 * 2;          // 8 MiB
static constexpr size_t VT_OFF = UT_OFF + WT_BYTES;
static constexpr size_t BP_OFF = VT_OFF + WT_BYTES;
static constexpr size_t BP_BYTES = 4096 * 4;
// h plane: [2 parity][4 group][16 row][1024 col] u16 (fp16)
static constexpr size_t HT_PLANE = (size_t)2 * 4 * 16 * 1024 * 2;    // 256 KiB
static constexpr size_t HHI_OFF = BP_OFF + BP_BYTES;
static constexpr size_t FLAG_OFF = HHI_OFF + HT_PLANE;
static constexpr size_t FLAG_BYTES = 4096;   // flags[g*64+cb] (1KB) + chunk cnt[4] @ +2048

__device__ __forceinline__ float bf2f(u32 u) {
    return __uint_as_float(u << 16);
}
__device__ __forceinline__ u16 f2bf(float f) {
    u32 u = __float_as_uint(f);
    u32 r = (u + 0x7FFFu + ((u >> 16) & 1u)) >> 16;
    return (u16)r;
}
__device__ __forceinline__ u16 f2h(float f) {
    _Float16 x = (_Float16)f;                     // RTN
    union { _Float16 h; u16 u; } cv;
    cv.h = x;
    return cv.u;
}

// fast gates: v_exp + v_rcp (err ~1e-7, far below bf16 pipeline noise)
__device__ __forceinline__ float fast_sigmoid(float x) {
    return __builtin_amdgcn_rcpf(1.f + __expf(-x));
}
__device__ __forceinline__ float fast_tanh(float x) {
    return 1.f - 2.f * __builtin_amdgcn_rcpf(1.f + __expf(2.f * x));
}

// 16B cache-bypassing load (full-64B-line MALL requests)
__device__ __forceinline__ u32x4 load16_uc(const u16* p) {
    u32x4 v;
    asm volatile("global_load_dwordx4 %0, %1, off sc0 sc1"
                 : "=v"(v)
                 : "v"(p));
    return v;
}

// 16B write-through store, MALL-ALLOCATING (sc0 sc1, no nt). Required for
// cross-XCD produce/consume of xu inside ONE kernel. Ledger: nt bypasses MALL
// allocation (consumer reads become HBM misses, +450us, R7); plain cached
// stores thrash MALL with dirty writebacks (FETCH 1.38GB, R8).
__device__ __forceinline__ void store16_wt(u16* p, u32x4 v) {
    asm volatile("global_store_dwordx4 %0, %1, off sc0 sc1"
                 :: "v"(p), "v"(v) : "memory");
}

// counted wait for h load j (4 loads issued; xu prefetch may be outstanding
// and is OLDER, so vmcnt(3-j) drains it first -- oldest-first is safe).
__device__ __forceinline__ void wait_vm4(int j, u32x4& a) {
    switch (j) {
    case 0:  asm volatile("s_waitcnt vmcnt(3)" : "+v"(a)); break;
    case 1:  asm volatile("s_waitcnt vmcnt(2)" : "+v"(a)); break;
    case 2:  asm volatile("s_waitcnt vmcnt(1)" : "+v"(a)); break;
    default: asm volatile("s_waitcnt vmcnt(0)" : "+v"(a)); break;
    }
}

// async global->LDS, 16B per lane (wave-uniform LDS base + lane*16)
__device__ __forceinline__ void gld16(const u16* g, u16* l) {
    __builtin_amdgcn_global_load_lds((const __attribute__((address_space(1))) void*)g,
                                     (__attribute__((address_space(3))) void*)l,
                                     16, 0, 0);
}

// xu t-chunk readiness gate (2048 tiles per chunk)
__device__ __forceinline__ void wait_chunk(const u32* cnt, int c) {
    for (;;) {
        u32 v = __hip_atomic_load(cnt + c, __ATOMIC_RELAXED, __HIP_MEMORY_SCOPE_AGENT);
        if (v >= 2048u) break;
        __builtin_amdgcn_s_sleep(8);
    }
    asm volatile("" ::: "memory");   // keep xu loads below the gate
}

// ------------- merged prep: cvt_x + U/V repack + bias pack + flag zero -------------
// One launch replaces 4 kernels + memset (saved ~140us of host-side gaps, R12).
// bx <  4096          : cvt_x body   (4096 x 256, 8 float4 each)
// bx <  6144          : repack body  (2048 blocks, verbatim round-5)
// bx <  6160          : bias body    (16 blocks)
// bx == 6160          : zero flags + chunk counters (agent-scope stores)
__global__ void __launch_bounds__(256) prep_kernel(
        const float* __restrict__ x,
        const float* U0, const float* U1, const float* U2, const float* U3,
        const float* V0, const float* V1, const float* V2, const float* V3,
        const float* b0, const float* b1, const float* b2, const float* b3,
        u16* __restrict__ xb, u16* __restrict__ UT, u16* __restrict__ VT,
        float* __restrict__ bp, u32* __restrict__ flags) {
    __shared__ u16 tile[64][65];
    int bx = blockIdx.x;
    int tid = threadIdx.x;

    if (bx < 4096) {            // ---- x fp32 -> bf16 ----
        const float4* x4 = (const float4*)x;
        uint2* xb4 = (uint2*)xb;
        int i = bx * 256 + tid;
#pragma unroll
        for (int k = 0; k < 8; ++k) {
            int idx = i + k * 1048576;
            float4 v = x4[idx];
            uint2 o;
            o.x = (u32)f2bf(v.x) | ((u32)f2bf(v.y) << 16);
            o.y = (u32)f2bf(v.z) | ((u32)f2bf(v.w) << 16);
            xb4[idx] = o;
        }
    } else if (bx < 6144) {     // ---- U/V repack (U->bf16, V->fp16) ----
        int rbx = bx - 4096;
        int mat = rbx >> 8;
        int rem = rbx & 255;
        int tf = rem >> 4, th = rem & 15;
        int f0 = tf * 64, h0 = th * 64;
        const float* srcs[8] = {U0, U1, U2, U3, V0, V1, V2, V3};
        const float* s = srcs[mat];
        u16* d = (mat < 4) ? UT : VT;
        bool isU = (mat < 4);
        int g = mat & 3;
        int c = tid & 63;
        int r = tid >> 6;
#pragma unroll
        for (int i = 0; i < 16; ++i) {
            int fr = r + i * 4;
            float v = s[(size_t)(f0 + fr) * 1024 + h0 + c];
            tile[fr][c] = isU ? f2bf(v) : f2h(v);
        }
        __syncthreads();
#pragma unroll
        for (int i = 0; i < 16; ++i) {
            int hcl = r + i * 4;
            d[(size_t)((h0 + hcl) * 4 + g) * 1024 + f0 + c] = tile[c][hcl];
        }
    } else if (bx < 6160) {     // ---- bias pack ----
        int n = (bx - 6144) * 256 + tid;
        int g = n & 3, hc = n >> 2;
        const float* bs[4] = {b0, b1, b2, b3};
        bp[n] = bs[g][hc];
    } else {                    // ---- zero flags + chunk counters ----
#pragma unroll
        for (int k = 0; k < 4; ++k)
            __hip_atomic_store(flags + tid * 4 + k, 0u, __ATOMIC_RELAXED,
                               __HIP_MEMORY_SCOPE_AGENT);
    }
}

// ------------- one 128x128 xU GEMM tile, 8 waves (512 threads) -------------
// R12 verbatim (best-known: kernel ~1985us, total 2150). Single-buffered
// staging; R13's dbuf and R15's swizzle both measured neutral-to-negative --
// the tile loop is bound by its lockstep barrier structure, which is
// irrelevant at phase A's ~70us. Chunk-ordered tau: tc=tau>>11,
// b=(tau&2047)>>5, nt=tau&31, mt=b*4+tc.
__device__ __forceinline__ void gemm_tile(int tau,
        const u16* __restrict__ xb, const u16* __restrict__ UT,
        const float* __restrict__ bp, u16* __restrict__ xu,
        u16* As, u16* Bs, u16* Cs, u32* cnt) {
    int tc = tau >> 11, rem = tau & 2047;
    int b = rem >> 5, nt = rem & 31, mt = b * 4 + tc;
    int tid = threadIdx.x;
    int lane = tid & 63, wv = tid >> 6;
    int wm = wv >> 2, wn = wv & 3;                // 2 x 4 wave grid
    int l15 = lane & 15, quad = lane >> 4;

    // staging: 512 threads x 16B = 8KB = one full [128][32] tile per inst
    int idr = tid >> 2, idk = (tid & 3) * 8;
    const u16* aS = xb + (size_t)(mt * 128 + idr) * 1024 + idk;
    const u16* bS = UT + (size_t)(nt * 128 + idr) * 1024 + idk;
    u16* aD = As + (size_t)tid * 8;
    u16* bD = Bs + (size_t)tid * 8;

    f32x4 acc[4][2];
#pragma unroll
    for (int i = 0; i < 4; ++i)
#pragma unroll
        for (int j = 0; j < 2; ++j) acc[i][j] = f32x4{0.f, 0.f, 0.f, 0.f};

    float biasv[2];
#pragma unroll
    for (int j = 0; j < 2; ++j) biasv[j] = bp[nt * 128 + wn * 32 + j * 16 + l15];

    for (int k0 = 0; k0 < 1024; k0 += 32) {
        gld16(aS + k0, aD);
        gld16(bS + k0, bD);
        __syncthreads();                          // compiler drains vmcnt first
        bf16x8 af[4], bfv[2];
#pragma unroll
        for (int i = 0; i < 4; ++i)
            af[i] = *(const bf16x8*)(As + (size_t)(wm * 64 + i * 16 + l15) * 32 + quad * 8);
#pragma unroll
        for (int j = 0; j < 2; ++j)
            bfv[j] = *(const bf16x8*)(Bs + (size_t)(wn * 32 + j * 16 + l15) * 32 + quad * 8);
#pragma unroll
        for (int i = 0; i < 4; ++i)
#pragma unroll
            for (int j = 0; j < 2; ++j)
                acc[i][j] = __builtin_amdgcn_mfma_f32_16x16x32_bf16(af[i], bfv[j], acc[i][j], 0, 0, 0);
        __syncthreads();                          // protect LDS before next stage
    }

    // acc -> LDS C-tile (row-pad 136 u16 kills the 64-aligned bank repeat)
#pragma unroll
    for (int i = 0; i < 4; ++i)
#pragma unroll
        for (int j = 0; j < 2; ++j)
#pragma unroll
            for (int rg = 0; rg < 4; ++rg)
                Cs[(size_t)(wm * 64 + i * 16 + quad * 4 + rg) * 136 + wn * 32 + j * 16 + l15] =
                    f2bf(acc[i][j][rg] + biasv[j]);
    __syncthreads();

    // coalesced write-through: 16 lanes cover one 256B row-segment
#pragma unroll
    for (int p = 0; p < 4; ++p) {
        int id = p * 512 + tid;
        int row = id >> 4, q = id & 15;
        u32x4 v = *(const u32x4*)(Cs + (size_t)row * 136 + q * 8);
        int gr = mt * 128 + row;
        int t_i = gr & 511, b_i = gr >> 9;
        store16_wt(xu + (((size_t)(t_i * 64 + b_i)) << 12) + nt * 128 + q * 8, v);
    }
    asm volatile("s_waitcnt vmcnt(0)" ::: "memory");
    __syncthreads();                              // all waves' stores MALL-acked
    if (tid == 0)
        __hip_atomic_fetch_add(cnt + tc, 1u, __ATOMIC_RELAXED, __HIP_MEMORY_SCOPE_AGENT);
}

// ------------- fused kernel: xU GEMM overlapped with the recurrent scan -------------
// R12/R6 structure -- the measured optimum of the overlap trade (R11 paced =
// worse; R16 more-serial = worse; R6 split = best). 256 blocks x 512 threads,
// 1/CU (118KB LDS). PHASE A: all blocks build xu t-chunk 0. Then blocks
// 0..127 run the round-5 scan; blocks 128..255 build chunks 1..3 (stride-128
// tile order). Chunk gating via per-chunk counters (target 2048).
__global__ void __launch_bounds__(512, 2) lstm_fused_kernel(
        const u16* __restrict__ xb, const u16* __restrict__ UT,
        const float* __restrict__ bp, u16* __restrict__ xu,
        const u16* __restrict__ VT, u16* hhi, u32* flags, u32* cnt,
        float* __restrict__ out) {
    __shared__ u16 As[128 * 32];                  // 8 KB
    __shared__ u16 Bs[128 * 32];                  // 8 KB
    __shared__ u16 Cs[128 * 136];                 // 34 KB
    __shared__ float zs[8][16][132];              // 67.6 KB

    int bx = blockIdx.x;

    // ---- PHASE A: chunk 0 on the full GPU ----
    for (int p = 0; p < 8; ++p)
        gemm_tile(bx * 8 + p, xb, UT, bp, xu, As, Bs, Cs, cnt);

    if (bx >= 128) {
        // ---- PHASE B: chunks 1..3 on blocks 128..255 ----
        int gid = bx - 128;
        for (int p = 0; p < 48; ++p)
            gemm_tile(2048 + p * 128 + gid, xb, UT, bp, xu, As, Bs, Cs, cnt);
        return;
    }

    // ---- recurrent scan (round-5 proven structure) ----
    int g  = bx & 3;
    int cb = bx >> 2;                             // 0..31
    int tid = threadIdx.x;
    int lane = tid & 63, wv = tid >> 6;           // wv 0..7
    int l15 = lane & 15, quad = lane >> 4;
    int r  = tid >> 5;                            // batch row within group, 0..15
    int hc = tid & 31;                            // h-col within block, 0..31

    // V fragments in registers (fp16, 128 VGPRs/lane, fixed across steps)
    f16x8 vfrag[8][4];
    {
        const u16* vb = VT + ((size_t)(cb * 128 + l15) * 1024) + wv * 128 + quad * 8;
#pragma unroll
        for (int nt = 0; nt < 8; ++nt)
#pragma unroll
            for (int j = 0; j < 4; ++j)
                vfrag[nt][j] = *(const f16x8*)(vb + (size_t)nt * 16 * 1024 + j * 32);
    }

    u32* gflags = flags + g * 64;
    int myp = 4 * wv + (lane & 3);                // producer polled by this lane

    float c = 0.f;
    float h = 0.f;

    wait_chunk(cnt, 0);
    uint2 xraw = *(const uint2*)(xu + ((size_t)(g * 16 + r) << 12) + cb * 128 + hc * 4);

    for (int t = 0; t < 512; ++t) {
        f32x4 acc[8];
#pragma unroll
        for (int nt = 0; nt < 8; ++nt) acc[nt] = f32x4{0.f, 0.f, 0.f, 0.f};

        if (t) {
            // 1) poll this wave's 4 producers (lanes replicate x16; ballot all-set)
            for (;;) {
                u32 f = __hip_atomic_load(gflags + myp, __ATOMIC_RELAXED,
                                          __HIP_MEMORY_SCOPE_AGENT);
                if (__ballot(f >= (u32)t) == ~0ull) break;
                __builtin_amdgcn_s_sleep(1);
            }
            asm volatile("" ::: "memory");        // keep h loads below the poll

            // 2) stream h fragments: 4x16B uncached loads, full-line MALL reads
            const u16* hB = hhi + (((size_t)(t & 1) * 4 + g) * 16 + l15) * 1024
                          + wv * 128 + quad * 8;
            u32x4 hv[4];
#pragma unroll
            for (int j = 0; j < 4; ++j)
                hv[j] = load16_uc(hB + j * 32);
#pragma unroll
            for (int j = 0; j < 4; ++j) {
                wait_vm4(j, hv[j]);               // counted wait, ties block MFMA hoist
                union { u32x4 q; f16x8 v; } ah;
                ah.q = hv[j];
#pragma unroll
                for (int nt = 0; nt < 8; ++nt)
                    acc[nt] = __builtin_amdgcn_mfma_f32_16x16x32_f16(ah.v, vfrag[nt][j], acc[nt], 0, 0, 0);
            }
        }

        // 3) split-K partial handoff: C layout col=l15, row=quad*4+rg
#pragma unroll
        for (int nt = 0; nt < 8; ++nt)
#pragma unroll
            for (int rg = 0; rg < 4; ++rg)
                zs[wv][quad * 4 + rg][nt * 16 + l15] = acc[nt][rg];
        __syncthreads();

        float4 s = {0.f, 0.f, 0.f, 0.f};
#pragma unroll
        for (int w = 0; w < 8; ++w) {
            float4 v = *(const float4*)&zs[w][r][hc * 4];
            s.x += v.x; s.y += v.y; s.z += v.z; s.w += v.w;
        }
        float z0 = s.x + bf2f(xraw.x & 0xFFFFu);
        float z1 = s.y + bf2f(xraw.x >> 16);
        float z2 = s.z + bf2f(xraw.y & 0xFFFFu);
        float z3 = s.w + bf2f(xraw.y >> 16);

        float it_ = fast_sigmoid(z0);
        float ft_ = fast_sigmoid(z1);
        float gt_ = fast_tanh(z2);
        float ot_ = fast_tanh(z3);   // reference uses tanh for output gate
        c = ft_ * c + it_ * gt_;
        h = ot_ * fast_tanh(c);

        if (t == 511) break;     // final h never read back

        // 4) publish h (single fp16 write-through) + drain (stores only) + flag
        size_t sidx = (((size_t)((t + 1) & 1) * 4 + g) * 16 + r) * 1024 + cb * 32 + hc;
        __hip_atomic_store(hhi + sidx, f2h(h), __ATOMIC_RELAXED,
                           __HIP_MEMORY_SCOPE_AGENT);
        asm volatile("s_waitcnt vmcnt(0)" ::: "memory");
        __syncthreads();          // also protects zs reuse next iteration
        if (tid == 0)
            __hip_atomic_store(gflags + cb, (u32)(t + 1), __ATOMIC_RELAXED,
                               __HIP_MEMORY_SCOPE_AGENT);

        // 5) prefetch next xu AFTER the flag (chunk-gated every 128 steps;
        //    gate is after the flag store so it never extends the publish path)
        if (((t + 1) & 127) == 0) wait_chunk(cnt, (t + 1) >> 7);
        xraw = *(const uint2*)(xu + ((size_t)((t + 1) * 64 + g * 16 + r) << 12) + cb * 128 + hc * 4);
    }

    out[(size_t)(g * 16 + r) * 1024 + cb * 32 + hc] = h;
}

extern "C" void kernel_launch(void* const* d_in, const int* in_sizes, int n_in,
                              void* d_out, int out_size, void* d_ws, size_t ws_size,
                              hipStream_t stream) {
    char* ws = (char*)d_ws;
    const float* x = (const float*)d_in[0];
    const float *U[4], *V[4], *b[4];
    for (int g = 0; g < 4; ++g) {
        U[g] = (const float*)d_in[1 + 3 * g];
        V[g] = (const float*)d_in[2 + 3 * g];
        b[g] = (const float*)d_in[3 + 3 * g];
    }
    u16*   xu = (u16*)(ws + XU_OFF);
    u16*   xb = (u16*)(ws + XB_OFF);
    u16*   UT = (u16*)(ws + UT_OFF);
    u16*   VT = (u16*)(ws + VT_OFF);
    float* bp = (float*)(ws + BP_OFF);
    u16*   hhi = (u16*)(ws + HHI_OFF);
    u32*   flags = (u32*)(ws + FLAG_OFF);
    u32*   cnt = (u32*)(ws + FLAG_OFF + 2048);
    float* out = (float*)d_out;

    // ONE prep launch: cvt + repack + bias + flag/cnt zero
    prep_kernel<<<6161, 256, 0, stream>>>(x,
                                          U[0], U[1], U[2], U[3],
                                          V[0], V[1], V[2], V[3],
                                          b[0], b[1], b[2], b[3],
                                          xb, UT, VT, bp, flags);

    void* args[] = {(void*)&xb, (void*)&UT, (void*)&bp, (void*)&xu,
                    (void*)&VT, (void*)&hhi, (void*)&flags, (void*)&cnt,
                    (void*)&out};
    hipLaunchCooperativeKernel((const void*)lstm_fused_kernel, dim3(256), dim3(512),
                               args, 0, stream);
}